// Round 1
// baseline (148.338 us; speedup 1.0000x reference)
//
#include <hip/hip_runtime.h>

#define CROP_S 14
#define NPIX   (CROP_S * CROP_S)   // 196
#define NCH    256

__global__ __launch_bounds__(256) void roi_crop_kernel(
    const float* __restrict__ f0, const float* __restrict__ f1,
    const float* __restrict__ f2, const float* __restrict__ f3,
    const float* __restrict__ proposals, float* __restrict__ out)
{
    const int n   = blockIdx.x;
    const int tid = threadIdx.x;

    // Per-proposal box (image coords)
    const float px0 = proposals[n * 7 + 1];
    const float py0 = proposals[n * 7 + 2];
    const float px1 = proposals[n * 7 + 3];
    const float py1 = proposals[n * 7 + 4];

    // Level selection: argmin over |sqrt(w*h) - base|, first-min tie-break
    const float size = sqrtf((px1 - px0) * (py1 - py0));
    int lvl = 0;
    float bd = fabsf(size - 8.0f);
    {
        float d1 = fabsf(size - 16.0f);
        if (d1 < bd) { bd = d1; lvl = 1; }
        float d2 = fabsf(size - 32.0f);
        if (d2 < bd) { bd = d2; lvl = 2; }
        float d3 = fabsf(size - 64.0f);
        if (d3 < bd) { bd = d3; lvl = 3; }
    }

    const float* f = (lvl == 0) ? f0 : (lvl == 1) ? f1 : (lvl == 2) ? f2 : f3;
    const float stride = (float)(2 << lvl);     // 2,4,8,16
    const int   M      = 256 >> lvl;            // H == W: 256,128,64,32
    const int   HW     = M * M;

    if (tid >= NPIX) return;

    const int y = tid / CROP_S;
    const int x = tid - y * CROP_S;

    // Scaled box coords (pow2 divide — exact)
    const float x0s = px0 / stride, y0s = py0 / stride;
    const float x1s = px1 / stride, y1s = py1 / stride;
    const float bw = (x1s - x0s) / (float)CROP_S;
    const float bh = (y1s - y0s) / (float)CROP_S;

    const float xs = x0s + ((float)x + 0.5f) * bw - 0.5f;
    const float ys = y0s + ((float)y + 0.5f) * bh - 0.5f;

    // floor/frac BEFORE clipping (matches reference)
    const float fx0 = floorf(xs); const float wx = xs - fx0;
    const float fy0 = floorf(ys); const float wy = ys - fy0;
    int xi0 = (int)fx0; xi0 = min(max(xi0, 0), M - 1);
    int xi1 = min(xi0 + 1, M - 1);
    int yi0 = (int)fy0; yi0 = min(max(yi0, 0), M - 1);
    int yi1 = min(yi0 + 1, M - 1);

    const float w00 = (1.0f - wy) * (1.0f - wx);
    const float w01 = (1.0f - wy) * wx;
    const float w10 = wy * (1.0f - wx);
    const float w11 = wy * wx;

    const int o00 = yi0 * M + xi0, o01 = yi0 * M + xi1;
    const int o10 = yi1 * M + xi0, o11 = yi1 * M + xi1;

    float* op = out + (size_t)n * NCH * NPIX + tid;
    const float* fp = f;   // batch index is always 0 (B == 1)

    #pragma unroll 4
    for (int c = 0; c < NCH; ++c) {
        const float v = w00 * fp[o00] + w01 * fp[o01]
                      + w10 * fp[o10] + w11 * fp[o11];
        op[(size_t)c * NPIX] = v;
        fp += HW;
    }
}

extern "C" void kernel_launch(void* const* d_in, const int* in_sizes, int n_in,
                              void* d_out, int out_size, void* d_ws, size_t ws_size,
                              hipStream_t stream) {
    const float* f0 = (const float*)d_in[0];
    const float* f1 = (const float*)d_in[1];
    const float* f2 = (const float*)d_in[2];
    const float* f3 = (const float*)d_in[3];
    const float* proposals = (const float*)d_in[4];
    float* out = (float*)d_out;

    const int N = in_sizes[4] / 7;   // 1024 proposals

    roi_crop_kernel<<<dim3(N), dim3(256), 0, stream>>>(f0, f1, f2, f3, proposals, out);
}

// Round 2
// 87.535 us; speedup vs baseline: 1.6946x; 1.6946x over previous
//
#include <hip/hip_runtime.h>

#define CROP_S 14
#define NPIX   (CROP_S * CROP_S)   // 196
#define NCH    256
#define CPB    32                   // channels per block
#define NGRP   (NCH / CPB)          // 8 blocks per proposal

__global__ __launch_bounds__(256) void roi_crop_kernel(
    const float* __restrict__ f0, const float* __restrict__ f1,
    const float* __restrict__ f2, const float* __restrict__ f3,
    const float* __restrict__ proposals, float* __restrict__ out)
{
    const int bid = blockIdx.x;
    const int n   = bid >> 3;        // proposal index
    const int cg  = bid & (NGRP - 1);
    const int c0  = cg * CPB;
    const int tid = threadIdx.x;

    if (tid >= NPIX) return;

    // Per-proposal box (image coords)
    const float px0 = proposals[n * 7 + 1];
    const float py0 = proposals[n * 7 + 2];
    const float px1 = proposals[n * 7 + 3];
    const float py1 = proposals[n * 7 + 4];

    // Level selection: argmin over |sqrt(w*h) - base|, first-min tie-break
    const float size = sqrtf((px1 - px0) * (py1 - py0));
    int lvl = 0;
    float bd = fabsf(size - 8.0f);
    {
        float d1 = fabsf(size - 16.0f);
        if (d1 < bd) { bd = d1; lvl = 1; }
        float d2 = fabsf(size - 32.0f);
        if (d2 < bd) { bd = d2; lvl = 2; }
        float d3 = fabsf(size - 64.0f);
        if (d3 < bd) { bd = d3; lvl = 3; }
    }

    const float* f = (lvl == 0) ? f0 : (lvl == 1) ? f1 : (lvl == 2) ? f2 : f3;
    const float stride = (float)(2 << lvl);     // 2,4,8,16
    const int   M      = 256 >> lvl;            // H == W
    const int   HW     = M * M;

    const int y = tid / CROP_S;
    const int x = tid - y * CROP_S;

    // Scaled box coords (pow2 divide — exact)
    const float x0s = px0 / stride, y0s = py0 / stride;
    const float x1s = px1 / stride, y1s = py1 / stride;
    const float bw = (x1s - x0s) / (float)CROP_S;
    const float bh = (y1s - y0s) / (float)CROP_S;

    const float xs = x0s + ((float)x + 0.5f) * bw - 0.5f;
    const float ys = y0s + ((float)y + 0.5f) * bh - 0.5f;

    // floor/frac BEFORE clipping (matches reference)
    const float fx0 = floorf(xs); const float wx = xs - fx0;
    const float fy0 = floorf(ys); const float wy = ys - fy0;
    int xi0 = (int)fx0; xi0 = min(max(xi0, 0), M - 1);
    int xi1 = min(xi0 + 1, M - 1);
    int yi0 = (int)fy0; yi0 = min(max(yi0, 0), M - 1);
    int yi1 = min(yi0 + 1, M - 1);

    const float w00 = (1.0f - wy) * (1.0f - wx);
    const float w01 = (1.0f - wy) * wx;
    const float w10 = wy * (1.0f - wx);
    const float w11 = wy * wx;

    const int o00 = yi0 * M + xi0, o01 = yi0 * M + xi1;
    const int o10 = yi1 * M + xi0, o11 = yi1 * M + xi1;

    const float* fp = f + (size_t)c0 * HW;
    float* op = out + (size_t)n * NCH * NPIX + (size_t)c0 * NPIX + tid;

    #pragma unroll 8
    for (int c = 0; c < CPB; ++c) {
        const float v = w00 * fp[o00] + w01 * fp[o01]
                      + w10 * fp[o10] + w11 * fp[o11];
        __builtin_nontemporal_store(v, op);
        op += NPIX;
        fp += HW;
    }
}

extern "C" void kernel_launch(void* const* d_in, const int* in_sizes, int n_in,
                              void* d_out, int out_size, void* d_ws, size_t ws_size,
                              hipStream_t stream) {
    const float* f0 = (const float*)d_in[0];
    const float* f1 = (const float*)d_in[1];
    const float* f2 = (const float*)d_in[2];
    const float* f3 = (const float*)d_in[3];
    const float* proposals = (const float*)d_in[4];
    float* out = (float*)d_out;

    const int N = in_sizes[4] / 7;   // 1024 proposals

    roi_crop_kernel<<<dim3(N * NGRP), dim3(256), 0, stream>>>(f0, f1, f2, f3, proposals, out);
}

// Round 3
// 78.898 us; speedup vs baseline: 1.8801x; 1.1095x over previous
//
#include <hip/hip_runtime.h>

#define CROP_S 14
#define NPIX   196                  // 14*14
#define NCH    256
#define CPB    16                   // channels per block
#define NGRP   (NCH / CPB)          // 16 blocks per proposal
#define PDIM   12                   // patch is 12x12 per channel (span provably <= 11)
#define PSZ    (PDIM * PDIM)        // 144
#define STAGE_TOT  (CPB * PSZ)      // 2304 = 9 * 256
#define INTERP_TOT (CPB * NPIX)     // 3136 = 12*256 + 64

__global__ __launch_bounds__(256) void roi_crop_kernel(
    const float* __restrict__ f0, const float* __restrict__ f1,
    const float* __restrict__ f2, const float* __restrict__ f3,
    const float* __restrict__ proposals, float* __restrict__ out)
{
    __shared__ float    s_patch[STAGE_TOT];   // [c][12][12]
    __shared__ float    s_wx[NPIX], s_wy[NPIX];
    __shared__ unsigned s_off[NPIX];          // 4 packed byte-indices into 12x12 patch

    const int bid = blockIdx.x;
    const int n   = bid >> 4;          // proposal
    const int cg  = bid & (NGRP - 1);  // channel group
    const int c0  = cg * CPB;
    const int tid = threadIdx.x;

    // ---- per-proposal box / level (redundant across threads; cheap, L2-hit) ----
    const float px0 = proposals[n * 7 + 1];
    const float py0 = proposals[n * 7 + 2];
    const float px1 = proposals[n * 7 + 3];
    const float py1 = proposals[n * 7 + 4];

    const float size = sqrtf((px1 - px0) * (py1 - py0));
    int lvl = 0;
    float bd = fabsf(size - 8.0f);
    {
        float d1 = fabsf(size - 16.0f);
        if (d1 < bd) { bd = d1; lvl = 1; }
        float d2 = fabsf(size - 32.0f);
        if (d2 < bd) { bd = d2; lvl = 2; }
        float d3 = fabsf(size - 64.0f);
        if (d3 < bd) { bd = d3; lvl = 3; }
    }

    const float* f = (lvl == 0) ? f0 : (lvl == 1) ? f1 : (lvl == 2) ? f2 : f3;
    const float stride = (float)(2 << lvl);   // 2,4,8,16 (pow2 -> exact divide)
    const int   M      = 256 >> lvl;          // H == W
    const int   HW     = M * M;

    const float x0s = px0 / stride, y0s = py0 / stride;
    const float x1s = px1 / stride, y1s = py1 / stride;
    const float bw = (x1s - x0s) / (float)CROP_S;
    const float bh = (y1s - y0s) / (float)CROP_S;

    // patch origin: floor of the minimal sample coordinate, clamped
    const int xlo = min(max((int)floorf(x0s + 0.5f * bw - 0.5f), 0), M - 1);
    const int ylo = min(max((int)floorf(y0s + 0.5f * bh - 0.5f), 0), M - 1);

    // ---- stage 16 channels x 12x12 patch into LDS (contiguous row loads) ----
    const float* fbase = f + (size_t)c0 * HW;
    #pragma unroll
    for (int it = 0; it < STAGE_TOT / 256; ++it) {
        const int sidx = it * 256 + tid;
        const int c    = sidx / PSZ;            // const-div
        const int rem  = sidx - c * PSZ;
        const int r    = rem / PDIM;            // const-div
        const int col  = rem - r * PDIM;
        const int gy   = min(ylo + r,   M - 1); // clamp replicates edge
        const int gx   = min(xlo + col, M - 1);
        s_patch[sidx] = fbase[(size_t)c * HW + gy * M + gx];
    }

    // ---- per-pixel bilinear coords (196 threads), shared by all channels ----
    if (tid < NPIX) {
        const int y = tid / CROP_S;
        const int x = tid - y * CROP_S;
        const float xs = x0s + ((float)x + 0.5f) * bw - 0.5f;
        const float ys = y0s + ((float)y + 0.5f) * bh - 0.5f;
        const float fx = floorf(xs), fy = floorf(ys);
        s_wx[tid] = xs - fx;                    // frac BEFORE clip (matches ref)
        s_wy[tid] = ys - fy;
        int xi0 = min(max((int)fx, 0), M - 1);
        int xi1 = min(xi0 + 1, M - 1);
        int yi0 = min(max((int)fy, 0), M - 1);
        int yi1 = min(yi0 + 1, M - 1);
        // relative patch indices (provably in [0,11]; clamp for safety)
        const unsigned ci0 = (unsigned)min(xi0 - xlo, PDIM - 1);
        const unsigned ci1 = (unsigned)min(xi1 - xlo, PDIM - 1);
        const unsigned ri0 = (unsigned)min(yi0 - ylo, PDIM - 1);
        const unsigned ri1 = (unsigned)min(yi1 - ylo, PDIM - 1);
        const unsigned o00 = ri0 * PDIM + ci0, o01 = ri0 * PDIM + ci1;
        const unsigned o10 = ri1 * PDIM + ci0, o11 = ri1 * PDIM + ci1;
        s_off[tid] = o00 | (o01 << 8) | (o10 << 16) | (o11 << 24);
    }
    __syncthreads();

    // ---- interpolate: flattened (c, pixel), full lanes, coalesced NT stores ----
    float* op = out + (size_t)n * NCH * NPIX + (size_t)c0 * NPIX;
    #pragma unroll 4
    for (int it = 0; it < (INTERP_TOT + 255) / 256; ++it) {
        const int idx = it * 256 + tid;
        if (idx < INTERP_TOT) {
            const int c = idx / NPIX;           // const-div
            const int p = idx - c * NPIX;
            const unsigned off = s_off[p];
            const float wx = s_wx[p], wy = s_wy[p];
            const float* pp = s_patch + c * PSZ;
            const float v00 = pp[ off        & 255u];
            const float v01 = pp[(off >> 8)  & 255u];
            const float v10 = pp[(off >> 16) & 255u];
            const float v11 = pp[ off >> 24        ];
            const float w00 = (1.0f - wy) * (1.0f - wx);
            const float w01 = (1.0f - wy) * wx;
            const float w10 = wy * (1.0f - wx);
            const float w11 = wy * wx;
            const float v = w00 * v00 + w01 * v01 + w10 * v10 + w11 * v11;
            __builtin_nontemporal_store(v, op + idx);
        }
    }
}

extern "C" void kernel_launch(void* const* d_in, const int* in_sizes, int n_in,
                              void* d_out, int out_size, void* d_ws, size_t ws_size,
                              hipStream_t stream) {
    const float* f0 = (const float*)d_in[0];
    const float* f1 = (const float*)d_in[1];
    const float* f2 = (const float*)d_in[2];
    const float* f3 = (const float*)d_in[3];
    const float* proposals = (const float*)d_in[4];
    float* out = (float*)d_out;

    const int N = in_sizes[4] / 7;   // 1024 proposals

    roi_crop_kernel<<<dim3(N * NGRP), dim3(256), 0, stream>>>(f0, f1, f2, f3, proposals, out);
}

// Round 4
// 64.980 us; speedup vs baseline: 2.2828x; 1.2142x over previous
//
#include <hip/hip_runtime.h>

#define CROP_S 14
#define NPIX   196                  // 14*14
#define NCH    256
#define CPB    16                   // channels per block
#define NGRP   (NCH / CPB)          // 16 blocks per proposal
#define PROWS  12                   // patch rows (span provably <= 12)
#define PCOLS  16                   // patch cols (span<=11 + <=3 align slack, float4-aligned)
#define PSZ    (PROWS * PCOLS)      // 192 floats per channel
#define STAGE_V4 (CPB * PSZ / 4)    // 768 float4 loads -> 3 per thread

__global__ __launch_bounds__(256) void roi_crop_kernel(
    const float* __restrict__ f0, const float* __restrict__ f1,
    const float* __restrict__ f2, const float* __restrict__ f3,
    const float* __restrict__ proposals, float* __restrict__ out)
{
    __shared__ float s_patch[CPB * PSZ];      // [c][12][16]

    const int bid = blockIdx.x;
    const int n   = bid >> 4;          // proposal
    const int cg  = bid & (NGRP - 1);  // channel group
    const int c0  = cg * CPB;
    const int tid = threadIdx.x;

    // ---- per-proposal box / level (uniform across block; L2-hit loads) ----
    const float px0 = proposals[n * 7 + 1];
    const float py0 = proposals[n * 7 + 2];
    const float px1 = proposals[n * 7 + 3];
    const float py1 = proposals[n * 7 + 4];

    const float size = sqrtf((px1 - px0) * (py1 - py0));
    int lvl = 0;
    float bd = fabsf(size - 8.0f);
    {
        float d1 = fabsf(size - 16.0f);
        if (d1 < bd) { bd = d1; lvl = 1; }
        float d2 = fabsf(size - 32.0f);
        if (d2 < bd) { bd = d2; lvl = 2; }
        float d3 = fabsf(size - 64.0f);
        if (d3 < bd) { bd = d3; lvl = 3; }
    }

    const float* f = (lvl == 0) ? f0 : (lvl == 1) ? f1 : (lvl == 2) ? f2 : f3;
    const float stride = (float)(2 << lvl);   // 2,4,8,16 (pow2 -> exact divide)
    const int   M      = 256 >> lvl;          // H == W
    const int   HW     = M * M;

    const float x0s = px0 / stride, y0s = py0 / stride;
    const float x1s = px1 / stride, y1s = py1 / stride;
    const float bw = (x1s - x0s) / (float)CROP_S;
    const float bh = (y1s - y0s) / (float)CROP_S;

    // patch origin: floor of minimal sample coord; x aligned down to float4
    const int ylo  = min(max((int)floorf(y0s + 0.5f * bh - 0.5f), 0), M - 1);
    int xlo4 = min(max((int)floorf(x0s + 0.5f * bw - 0.5f), 0), M - 1) & ~3;
    xlo4 = min(xlo4, M - PCOLS);              // vector loads stay inside tensor

    // ---- stage CPB channels x 12x16 patch via float4 (3 per thread) ----
    {
        const float* fbase = f + (size_t)c0 * HW + xlo4;
        #pragma unroll
        for (int it = 0; it < STAGE_V4 / 256; ++it) {
            const int sidx = it * 256 + tid;         // [0,768)
            const int c    = sidx / (PSZ / 4);       // /48
            const int rem  = sidx - c * (PSZ / 4);
            const int r    = rem >> 2;               // row 0..11
            const int q    = rem & 3;                // col quad
            const int gy   = min(ylo + r, M - 1);    // edge-replicate rows
            const float4 v = *reinterpret_cast<const float4*>(
                fbase + (size_t)c * HW + gy * M + q * 4);
            *reinterpret_cast<float4*>(&s_patch[sidx * 4]) = v;
        }
    }
    __syncthreads();

    if (tid >= NPIX) return;

    // ---- per-pixel bilinear state: registers, computed once ----
    const int y = tid / CROP_S;
    const int x = tid - y * CROP_S;
    const float xs = x0s + ((float)x + 0.5f) * bw - 0.5f;
    const float ys = y0s + ((float)y + 0.5f) * bh - 0.5f;
    const float fx = floorf(xs), fy = floorf(ys);
    const float wx = xs - fx;                 // frac BEFORE clip (matches ref)
    const float wy = ys - fy;
    int xi0 = min(max((int)fx, 0), M - 1);
    int xi1 = min(xi0 + 1, M - 1);
    int yi0 = min(max((int)fy, 0), M - 1);
    int yi1 = min(yi0 + 1, M - 1);
    // patch-relative indices (clamped for safety; provably in range)
    const int ci0 = min(xi0 - xlo4, PCOLS - 1);
    const int ci1 = min(xi1 - xlo4, PCOLS - 1);
    const int ri0 = min(yi0 - ylo, PROWS - 1);
    const int ri1 = min(yi1 - ylo, PROWS - 1);
    const int o00 = ri0 * PCOLS + ci0, o01 = ri0 * PCOLS + ci1;
    const int o10 = ri1 * PCOLS + ci0, o11 = ri1 * PCOLS + ci1;

    const float w00 = (1.0f - wy) * (1.0f - wx);
    const float w01 = (1.0f - wy) * wx;
    const float w10 = wy * (1.0f - wx);
    const float w11 = wy * wx;

    float* op = out + (size_t)n * NCH * NPIX + (size_t)c0 * NPIX + tid;

    #pragma unroll
    for (int c = 0; c < CPB; ++c) {
        const float* pp = s_patch + c * PSZ;
        const float v = w00 * pp[o00] + w01 * pp[o01]
                      + w10 * pp[o10] + w11 * pp[o11];
        __builtin_nontemporal_store(v, op);
        op += NPIX;
    }
}

extern "C" void kernel_launch(void* const* d_in, const int* in_sizes, int n_in,
                              void* d_out, int out_size, void* d_ws, size_t ws_size,
                              hipStream_t stream) {
    const float* f0 = (const float*)d_in[0];
    const float* f1 = (const float*)d_in[1];
    const float* f2 = (const float*)d_in[2];
    const float* f3 = (const float*)d_in[3];
    const float* proposals = (const float*)d_in[4];
    float* out = (float*)d_out;

    const int N = in_sizes[4] / 7;   // 1024 proposals

    roi_crop_kernel<<<dim3(N * NGRP), dim3(256), 0, stream>>>(f0, f1, f2, f3, proposals, out);
}